// Round 10
// baseline (149.747 us; speedup 1.0000x reference)
//
#include <hip/hip_runtime.h>

#define EPSF 1e-20f

typedef float v2f __attribute__((ext_vector_type(2)));
typedef float v4f __attribute__((ext_vector_type(4)));

constexpr int B_ = 2, C_ = 32, O_ = 32, H_ = 256, W_ = 512;
constexpr int HO = 254, WO = 510;
constexpr int HW  = H_ * W_;        // 131072
constexpr int PLO = HO * WO;        // 129540
constexpr int OUT1 = B_ * O_ * PLO;
constexpr int IMG  = B_ * C_ * HW;  // 8,388,608
constexpr int WT2  = 256;           // K2 tile width (pixels per block)
constexpr int NB1  = IMG / 4 / 256; // 8192 streaming blocks in K1

__device__ __forceinline__ float sp_(float x) { return log1pf(expf(x)); }
__device__ __forceinline__ float rcp_(float x) { return __builtin_amdgcn_rcpf(x); }

// unaligned-tolerant vector loads (4B-aligned ok; HW supports dwordx4 @ 4B)
__device__ __forceinline__ uint4 ld_u4(const unsigned* p) { uint4 v; __builtin_memcpy(&v, p, 16); return v; }
__device__ __forceinline__ uint2 ld_u2(const unsigned* p) { uint2 v; __builtin_memcpy(&v, p, 8);  return v; }
__device__ __forceinline__ v4f   ld_f4(const float* p)    { v4f  v; __builtin_memcpy(&v, p, 16); return v; }

// pack two floats as bf16(RN) into one uint: low16 = P, high16 = Q
__device__ __forceinline__ unsigned bfpack(float g, float c) {
  unsigned ug = __float_as_uint(g);
  unsigned uc = __float_as_uint(c);
  ug = ug + 0x7FFFu + ((ug >> 16) & 1u);
  uc = uc + 0x7FFFu + ((uc >> 16) & 1u);
  return (ug >> 16) | (uc & 0xFFFF0000u);
}
__device__ __forceinline__ float bf_lo(unsigned u) { return __uint_as_float(u << 16); }
__device__ __forceinline__ float bf_hi(unsigned u) { return __uint_as_float(u & 0xFFFF0000u); }

// ---------------------------------------------------------------------------
// K1: per-pixel vertical fusion -> packed bf16 (P, Q) where
//   P = gy_f * cgy_f = (a*gy + cfd*gfd) / (w+1)     [the (a+cfd) div cancels]
//   Q = cgy_f        = (a + cfd) / (w+1)
// Block NB1 (extra last block) performs the weight setup concurrently:
//   params: [0]=w [1]=sum(sw) [2]=sum(cw) [16..304)=sw[c][k] [304..1328)=cwT[c][o]
// ---------------------------------------------------------------------------
__global__ __launch_bounds__(256) void k1_gyf(const float* __restrict__ d,
                                              const float* __restrict__ cd,
                                              const float* __restrict__ s,
                                              const float* __restrict__ gy,
                                              const float* __restrict__ cgy,
                                              const float* __restrict__ w_prop,
                                              const float* __restrict__ spw,
                                              const float* __restrict__ chw,
                                              float* __restrict__ params,
                                              unsigned* __restrict__ I) {
  __shared__ float red[256];
  const int t = threadIdx.x;

  if (blockIdx.x == NB1) {            // ---- setup block ----
    float l1 = 0.f;
    for (int i = t; i < 288; i += 256) { float v = sp_(spw[i]); params[16 + i] = v; l1 += v; }
    red[t] = l1; __syncthreads();
    for (int k = 128; k > 0; k >>= 1) { if (t < k) red[t] += red[t + k]; __syncthreads(); }
    float SW = red[0]; __syncthreads();
    float l2 = 0.f;
    for (int i = t; i < 1024; i += 256) {
      int o = i >> 5, c = i & 31;
      float v = sp_(chw[o * C_ + c]);
      params[304 + c * O_ + o] = v;   // transposed store
      l2 += v;
    }
    red[t] = l2; __syncthreads();
    for (int k = 128; k > 0; k >>= 1) { if (t < k) red[t] += red[t + k]; __syncthreads(); }
    if (t == 0) { params[0] = sp_(w_prop[0]); params[1] = SW; params[2] = red[0]; }
    return;
  }

  const float w      = sp_(w_prop[0]);   // computed inline (no params dependency)
  const float inv_w1 = rcp_(w + 1.0f);
  const int idx = blockIdx.x * 256 + t;
  const long i4 = (long)idx * 4;
  const int h = (int)((i4 >> 9) & (H_ - 1));
  const long up = (h == 0)      ? i4 + (long)(H_ - 1) * W_ : i4 - W_;
  const long dn = (h == H_ - 1) ? i4 - (long)(H_ - 1) * W_ : i4 + W_;

  float4 duv = *(const float4*)(d + up);
  float4 ddv = *(const float4*)(d + dn);
  float4 sv  = *(const float4*)(s + i4);
  float4 suv = *(const float4*)(s + up);
  float4 sdv = *(const float4*)(s + dn);
  float4 cduv = (h == 0)      ? make_float4(0.f, 0.f, 0.f, 0.f) : *(const float4*)(cd + up);
  float4 cddv = (h == H_ - 1) ? make_float4(0.f, 0.f, 0.f, 0.f) : *(const float4*)(cd + dn);
  float4 gyv  = *(const float4*)(gy + i4);
  float4 cgyv = *(const float4*)(cgy + i4);

  const float* pdu = (const float*)&duv;  const float* pdd = (const float*)&ddv;
  const float* ps  = (const float*)&sv;   const float* psu = (const float*)&suv;
  const float* psd = (const float*)&sdv;  const float* pcu = (const float*)&cduv;
  const float* pcd = (const float*)&cddv; const float* pg  = (const float*)&gyv;
  const float* pc  = (const float*)&cgyv;

  uint4 o;
  unsigned* po = (unsigned*)&o;
#pragma unroll
  for (int j = 0; j < 4; ++j) {
    const float cu = pcu[j], cdn = pcd[j];
    const float cfd = ps[j] * psu[j] * psd[j] * cu * cu;           // cd_up twice (faithful)
    const float height = (cu * pdu[j] + cdn * pdd[j]) * rcp_(cu + cdn + EPSF);
    const float gfd = (pdd[j] - pdu[j]) * 0.5f * rcp_(height + EPSF);
    const float a = w * pc[j];
    const float P = (a * pg[j] + cfd * gfd) * inv_w1;   // gy_f * cgy_f (div cancels)
    const float Q = (a + cfd) * inv_w1;                 // cgy_f
    po[j] = bfpack(P, Q);
  }
  *(uint4*)(I + i4) = o;
}

// ---------------------------------------------------------------------------
// K2: fused 3x3 grouped conv + 1x1 channel mix. 1024 threads, 256-px tile.
// Grid (2, 254, 2): x-tiles at wo0 = {0, 254} OVERLAP by 2 px so every load
// stays in-bounds and phase B needs no mask (px 254/255 of tile 0 duplicate
// px 0/1 of tile 1 -- identical deterministic values).
// Phase A: wave = 2 channels (wv = t>>6), lane = pixel QUAD; spr loads are
//          dwordx4 (1KB/wave per tap), I loads uint4+uint2. 30 VMEM/thread.
// Phase B: px = t&255, o-group = t>>8 (wave-uniform); ds_read_b64 +
//          v_pk_fma channel mix; weights via wave-uniform s_loads.
// ---------------------------------------------------------------------------
__global__ __launch_bounds__(1024) void k2_fused(const unsigned* __restrict__ I,
                                                 const float* __restrict__ spr,
                                                 const float* __restrict__ params,
                                                 const float* __restrict__ bias,
                                                 float* __restrict__ out) {
  __shared__ v2f AB[C_][WT2];   // [c][px] (g,q); 32*256*8 = 65536 B exactly

  const int b   = blockIdx.z;
  const int ho  = blockIdx.y;
  const int wo0 = blockIdx.x * (WT2 - 2);   // {0, 254}
  const int t   = threadIdx.x;

  const float invSW = rcp_(params[1]);
  const float invCW = rcp_(params[2]);

  // ---- Phase A ----
  const int ql = t & 63;                                    // quad lane: px 4ql..4ql+3
  const int wv = __builtin_amdgcn_readfirstlane(t >> 6);    // 0..15, wave-uniform
  const int wq = wo0 + 4 * ql;                              // global wo of quad (<= 506)

#pragma unroll
  for (int it = 0; it < 2; ++it) {
    const int c = wv * 2 + it;
    const unsigned* Ip = I + (b * C_ + c) * HW + ho * W_ + wq;
    const float*    sp = spr + (long)(b * C_ + c) * 9 * PLO + (long)ho * WO + wq;

    // 6 I loads (3 rows x [uint4 + uint2] covering px wq..wq+5)
    uint4 A0 = ld_u4(Ip);            uint2 E0 = ld_u2(Ip + 4);
    uint4 A1 = ld_u4(Ip + W_);       uint2 E1 = ld_u2(Ip + W_ + 4);
    uint4 A2 = ld_u4(Ip + 2 * W_);   uint2 E2 = ld_u2(Ip + 2 * W_ + 4);
    // 9 spr loads (dwordx4)
    v4f sp4[9];
#pragma unroll
    for (int k = 0; k < 9; ++k) sp4[k] = ld_f4(sp + (long)k * PLO);

    // unpack 3 rows x 6 px of (P,Q)
    float P[3][6], Q[3][6];
    const unsigned r0[6] = {A0.x, A0.y, A0.z, A0.w, E0.x, E0.y};
    const unsigned r1[6] = {A1.x, A1.y, A1.z, A1.w, E1.x, E1.y};
    const unsigned r2[6] = {A2.x, A2.y, A2.z, A2.w, E2.x, E2.y};
#pragma unroll
    for (int j = 0; j < 6; ++j) {
      P[0][j] = bf_lo(r0[j]); Q[0][j] = bf_hi(r0[j]);
      P[1][j] = bf_lo(r1[j]); Q[1][j] = bf_hi(r1[j]);
      P[2][j] = bf_lo(r2[j]); Q[2][j] = bf_hi(r2[j]);
    }

    const float* swc = params + 16 + c * 9;   // wave-uniform -> s_load
    v4f nom = (v4f){0.f, 0.f, 0.f, 0.f};
    v4f den = (v4f){0.f, 0.f, 0.f, 0.f};
#pragma unroll
    for (int i = 0; i < 3; ++i) {
#pragma unroll
      for (int j = 0; j < 3; ++j) {
        const v4f tk = sp4[i * 3 + j] * swc[i * 3 + j];
        nom += tk * (v4f){P[i][j], P[i][j + 1], P[i][j + 2], P[i][j + 3]};
        den += tk * (v4f){Q[i][j], Q[i][j + 1], Q[i][j + 2], Q[i][j + 3]};
      }
    }
    // two b128 stores: (g,q) pairs for px 4ql..4ql+3
    *(v4f*)&AB[c][4 * ql]     = (v4f){nom.x * invSW, den.x * invSW, nom.y * invSW, den.y * invSW};
    *(v4f*)&AB[c][4 * ql + 2] = (v4f){nom.z * invSW, den.z * invSW, nom.w * invSW, den.w * invSW};
  }
  __syncthreads();

  // ---- Phase B ----
  const int px = t & 255;
  const int og = __builtin_amdgcn_readfirstlane(t >> 8);  // 0..3, wave-uniform
  const float* cwT = params + 304;                        // [c][o], uniform -> s_load

  v2f acc[8];
#pragma unroll
  for (int oj = 0; oj < 8; ++oj) acc[oj] = (v2f){0.f, 0.f};
#pragma unroll
  for (int c = 0; c < C_; ++c) {
    const v2f ab = AB[c][px];                // ds_read_b64, conflict-free
#pragma unroll
    for (int oj = 0; oj < 8; ++oj)
      acc[oj] += ab * cwT[c * O_ + og * 8 + oj];   // v_pk_fma_f32
  }

  const long obase = (long)b * O_ * PLO + (long)ho * WO + wo0 + px;  // always < WO
#pragma unroll
  for (int oj = 0; oj < 8; ++oj) {
    const int o = og * 8 + oj;
    out[obase + (long)o * PLO]        = acc[oj].x * rcp_(acc[oj].y + EPSF) + bias[o];
    out[OUT1 + obase + (long)o * PLO] = acc[oj].y * invCW;
  }
}

// ---------------------------------------------------------------------------
extern "C" void kernel_launch(void* const* d_in, const int* in_sizes, int n_in,
                              void* d_out, int out_size, void* d_ws, size_t ws_size,
                              hipStream_t stream) {
  const float* d      = (const float*)d_in[0];
  const float* cd     = (const float*)d_in[1];
  const float* s      = (const float*)d_in[2];
  // d_in[3]=cs, d_in[4]=gx, d_in[5]=cgx unused by the reference
  const float* gy     = (const float*)d_in[6];
  const float* cgy    = (const float*)d_in[7];
  const float* spr    = (const float*)d_in[8];
  const float* w_prop = (const float*)d_in[9];
  const float* spw    = (const float*)d_in[10];
  const float* chw    = (const float*)d_in[11];
  const float* bias   = (const float*)d_in[12];
  float* out = (float*)d_out;

  float* params = (float*)d_ws;                       // 4096 floats reserved
  unsigned* I   = (unsigned*)d_ws + 4096;             // packed bf16 intermediate (33.5 MB)

  // K1 (+1 setup block folded in, runs concurrently with streaming blocks)
  k1_gyf<<<NB1 + 1, 256, 0, stream>>>(d, cd, s, gy, cgy, w_prop, spw, chw, params, I);

  dim3 g2(2, HO, B_);   // (2, 254, 2) = 1016 blocks x 1024 threads
  k2_fused<<<g2, 1024, 0, stream>>>(I, spr, params, bias, out);
}

// Round 11
// 134.942 us; speedup vs baseline: 1.1097x; 1.1097x over previous
//
#include <hip/hip_runtime.h>

#define EPSF 1e-20f

typedef float v2f __attribute__((ext_vector_type(2)));
typedef float v4f __attribute__((ext_vector_type(4)));

constexpr int B_ = 2, C_ = 32, O_ = 32, H_ = 256, W_ = 512;
constexpr int HO = 254, WO = 510;
constexpr int HW  = H_ * W_;        // 131072
constexpr int PLO = HO * WO;        // 129540
constexpr int OUT1 = B_ * O_ * PLO;
constexpr int IMG  = B_ * C_ * HW;  // 8,388,608
constexpr int WT2  = 128;           // K2 tile width (pixels per block)
constexpr int NB1  = IMG / 4 / 256; // 8192 streaming blocks in K1
constexpr int NB2  = 4 * HO * B_;   // 2032 K2 blocks (2032 = 8*254, swizzle-bijective)

__device__ __forceinline__ float sp_(float x) { return log1pf(expf(x)); }
__device__ __forceinline__ float rcp_(float x) { return __builtin_amdgcn_rcpf(x); }

// pack two floats as bf16(RN) into one uint: low16 = P, high16 = Q
__device__ __forceinline__ unsigned bfpack(float g, float c) {
  unsigned ug = __float_as_uint(g);
  unsigned uc = __float_as_uint(c);
  ug = ug + 0x7FFFu + ((ug >> 16) & 1u);
  uc = uc + 0x7FFFu + ((uc >> 16) & 1u);
  return (ug >> 16) | (uc & 0xFFFF0000u);
}
__device__ __forceinline__ float bf_lo(unsigned u) { return __uint_as_float(u << 16); }
__device__ __forceinline__ float bf_hi(unsigned u) { return __uint_as_float(u & 0xFFFF0000u); }

// ---------------------------------------------------------------------------
// K1: per-pixel vertical fusion -> packed bf16 (P, Q) where
//   P = gy_f * cgy_f = (a*gy + cfd*gfd) / (w+1)     [the (a+cfd) div cancels]
//   Q = cgy_f        = (a + cfd) / (w+1)
// Block NB1 (extra last block) performs the weight setup concurrently:
//   params: [0]=w [1]=sum(sw) [2]=sum(cw) [16..304)=sw[c][k] [304..1328)=cwT[c][o]
// ---------------------------------------------------------------------------
__global__ __launch_bounds__(256) void k1_gyf(const float* __restrict__ d,
                                              const float* __restrict__ cd,
                                              const float* __restrict__ s,
                                              const float* __restrict__ gy,
                                              const float* __restrict__ cgy,
                                              const float* __restrict__ w_prop,
                                              const float* __restrict__ spw,
                                              const float* __restrict__ chw,
                                              float* __restrict__ params,
                                              unsigned* __restrict__ I) {
  __shared__ float red[256];
  const int t = threadIdx.x;

  if (blockIdx.x == NB1) {            // ---- setup block ----
    float l1 = 0.f;
    for (int i = t; i < 288; i += 256) { float v = sp_(spw[i]); params[16 + i] = v; l1 += v; }
    red[t] = l1; __syncthreads();
    for (int k = 128; k > 0; k >>= 1) { if (t < k) red[t] += red[t + k]; __syncthreads(); }
    float SW = red[0]; __syncthreads();
    float l2 = 0.f;
    for (int i = t; i < 1024; i += 256) {
      int o = i >> 5, c = i & 31;
      float v = sp_(chw[o * C_ + c]);
      params[304 + c * O_ + o] = v;   // transposed store
      l2 += v;
    }
    red[t] = l2; __syncthreads();
    for (int k = 128; k > 0; k >>= 1) { if (t < k) red[t] += red[t + k]; __syncthreads(); }
    if (t == 0) { params[0] = sp_(w_prop[0]); params[1] = SW; params[2] = red[0]; }
    return;
  }

  const float w      = sp_(w_prop[0]);   // computed inline (no params dependency)
  const float inv_w1 = rcp_(w + 1.0f);
  const int idx = blockIdx.x * 256 + t;
  const long i4 = (long)idx * 4;
  const int h = (int)((i4 >> 9) & (H_ - 1));
  const long up = (h == 0)      ? i4 + (long)(H_ - 1) * W_ : i4 - W_;
  const long dn = (h == H_ - 1) ? i4 - (long)(H_ - 1) * W_ : i4 + W_;

  float4 duv = *(const float4*)(d + up);
  float4 ddv = *(const float4*)(d + dn);
  float4 sv  = *(const float4*)(s + i4);
  float4 suv = *(const float4*)(s + up);
  float4 sdv = *(const float4*)(s + dn);
  float4 cduv = (h == 0)      ? make_float4(0.f, 0.f, 0.f, 0.f) : *(const float4*)(cd + up);
  float4 cddv = (h == H_ - 1) ? make_float4(0.f, 0.f, 0.f, 0.f) : *(const float4*)(cd + dn);
  float4 gyv  = *(const float4*)(gy + i4);
  float4 cgyv = *(const float4*)(cgy + i4);

  const float* pdu = (const float*)&duv;  const float* pdd = (const float*)&ddv;
  const float* ps  = (const float*)&sv;   const float* psu = (const float*)&suv;
  const float* psd = (const float*)&sdv;  const float* pcu = (const float*)&cduv;
  const float* pcd = (const float*)&cddv; const float* pg  = (const float*)&gyv;
  const float* pc  = (const float*)&cgyv;

  uint4 o;
  unsigned* po = (unsigned*)&o;
#pragma unroll
  for (int j = 0; j < 4; ++j) {
    const float cu = pcu[j], cdn = pcd[j];
    const float cfd = ps[j] * psu[j] * psd[j] * cu * cu;           // cd_up twice (faithful)
    const float height = (cu * pdu[j] + cdn * pdd[j]) * rcp_(cu + cdn + EPSF);
    const float gfd = (pdd[j] - pdu[j]) * 0.5f * rcp_(height + EPSF);
    const float a = w * pc[j];
    const float P = (a * pg[j] + cfd * gfd) * inv_w1;   // gy_f * cgy_f (div cancels)
    const float Q = (a + cfd) * inv_w1;                 // cgy_f
    po[j] = bfpack(P, Q);
  }
  *(uint4*)(I + i4) = o;
}

// ---------------------------------------------------------------------------
// K2: fused 3x3 grouped conv + 1x1 channel mix. 512 threads, 128-px tile.
// Flat 2032-block grid with XCD-aware swizzle: swz = (bid&7)*254 + (bid>>3)
// (bijective; each XCD owns a contiguous (b, ho-range) chunk -> the 3x
// I-row reuse across ho-neighbors stays in one XCD's L2).
// Phase A: wave = channel-group of 4 (cg = t>>6 wave-uniform), lane = px-pair;
//          512B wave-contiguous loads; 3 packed ops per tap; sw via s_load.
//          AB = (nom*invSW, den*invSW) = (gy_sp*cgy_sp, cgy_sp), eps folded.
// Phase B: lane = px-pair, wave = 4-o group; ds_read_b128 per channel +
//          v_pk_fma mix; float2 stores -> 512B/wave write transactions.
// ---------------------------------------------------------------------------
__global__ __launch_bounds__(512) void k2_fused(const unsigned* __restrict__ I,
                                                const float* __restrict__ spr,
                                                const float* __restrict__ params,
                                                const float* __restrict__ bias,
                                                float* __restrict__ out) {
  __shared__ v2f AB[C_][WT2 + 2];   // [c][px], pad 2 -> 130 v2f per row

  const int bid = blockIdx.x;                            // 0..2031
  const int swz = (bid & 7) * (NB2 / 8) + (bid >> 3);    // XCD-contiguous chunks
  const int xt  = swz & 3;
  const int ho  = (swz >> 2) % HO;
  const int b   = swz / (4 * HO);
  const int wo0 = xt * WT2;
  const int t   = threadIdx.x;

  const float invSW = rcp_(params[1]);
  const float invCW = rcp_(params[2]);

  // ---- Phase A ----
  const int pp = t & 63;                                     // pixel pair: px = 2pp, 2pp+1
  const int cg = __builtin_amdgcn_readfirstlane(t >> 6);     // 0..7, wave-uniform
  const int wo  = wo0 + 2 * pp;
  const int wos = (wo <= WO - 2) ? wo : (WO - 2);            // even clamp (508)

#pragma unroll
  for (int ci = 0; ci < 4; ++ci) {
    const int c = cg * 4 + ci;
    const unsigned* Ip = I + (b * C_ + c) * HW + ho * W_ + wos;
    uint2 r0a = *(const uint2*)(Ip);
    uint2 r0b = *(const uint2*)(Ip + 2);
    uint2 r1a = *(const uint2*)(Ip + W_);
    uint2 r1b = *(const uint2*)(Ip + W_ + 2);
    uint2 r2a = *(const uint2*)(Ip + 2 * W_);
    uint2 r2b = *(const uint2*)(Ip + 2 * W_ + 2);

    const float* sp = spr + (long)(b * C_ + c) * 9 * PLO + (long)ho * WO + wos;
    v2f spv[9];
#pragma unroll
    for (int k = 0; k < 9; ++k) spv[k] = *(const v2f*)(sp + (long)k * PLO);

    unsigned urow[3][4] = {{r0a.x, r0a.y, r0b.x, r0b.y},
                           {r1a.x, r1a.y, r1b.x, r1b.y},
                           {r2a.x, r2a.y, r2b.x, r2b.y}};
    float P[3][4], Q[3][4];
#pragma unroll
    for (int i = 0; i < 3; ++i)
#pragma unroll
      for (int j = 0; j < 4; ++j) { P[i][j] = bf_lo(urow[i][j]); Q[i][j] = bf_hi(urow[i][j]); }

    const float* swc = params + 16 + c * 9;   // wave-uniform -> s_load
    v2f nom = (v2f){0.f, 0.f};
    v2f den = (v2f){0.f, 0.f};
#pragma unroll
    for (int i = 0; i < 3; ++i) {
#pragma unroll
      for (int j = 0; j < 3; ++j) {
        const v2f tk = spv[i * 3 + j] * swc[i * 3 + j];           // pk_mul
        nom += tk * (v2f){P[i][j], P[i][j + 1]};                  // pk_fma
        den += tk * (v2f){Q[i][j], Q[i][j + 1]};                  // pk_fma
      }
    }
    // single b128 store: (px0.g, px0.c, px1.g, px1.c)
    *(v4f*)&AB[c][2 * pp] = (v4f){nom.x * invSW, den.x * invSW,
                                  nom.y * invSW, den.y * invSW};
  }
  __syncthreads();

  // ---- Phase B ----
  const int pe  = t & 63;                                  // pixel pair: px = 2pe, 2pe+1
  const int og  = __builtin_amdgcn_readfirstlane(t >> 6);  // 0..7 -> o = og*4 .. og*4+3
  const int wob = wo0 + 2 * pe;

  const float* cwT = params + 304;     // [c][o], uniform indices -> s_load
  v2f a0[4], a1[4];                    // [oj][pixel 0/1 of pair]
#pragma unroll
  for (int oj = 0; oj < 4; ++oj) { a0[oj] = (v2f){0.f, 0.f}; a1[oj] = (v2f){0.f, 0.f}; }

#pragma unroll
  for (int c = 0; c < C_; ++c) {
    const v4f abp = *(const v4f*)&AB[c][2 * pe];   // ds_read_b128: (g0,q0,g1,q1)
    const v2f ab0 = (v2f){abp.x, abp.y};
    const v2f ab1 = (v2f){abp.z, abp.w};
#pragma unroll
    for (int oj = 0; oj < 4; ++oj) {
      const float wv = cwT[c * O_ + og * 4 + oj];
      a0[oj] += ab0 * wv;                          // v_pk_fma_f32
      a1[oj] += ab1 * wv;
    }
  }

  if (wob < WO) {                                  // full pair valid (WO even)
    const long obase = (long)b * O_ * PLO + (long)ho * WO + wob;
#pragma unroll
    for (int oj = 0; oj < 4; ++oj) {
      const int o = og * 4 + oj;
      const float bv = bias[o];                    // uniform -> s_load
      const float2 rg = make_float2(a0[oj].x * rcp_(a0[oj].y + EPSF) + bv,
                                    a1[oj].x * rcp_(a1[oj].y + EPSF) + bv);
      const float2 rc = make_float2(a0[oj].y * invCW, a1[oj].y * invCW);
      *(float2*)(out + obase + (long)o * PLO)        = rg;   // 512B/wave stores
      *(float2*)(out + OUT1 + obase + (long)o * PLO) = rc;
    }
  }
}

// ---------------------------------------------------------------------------
extern "C" void kernel_launch(void* const* d_in, const int* in_sizes, int n_in,
                              void* d_out, int out_size, void* d_ws, size_t ws_size,
                              hipStream_t stream) {
  const float* d      = (const float*)d_in[0];
  const float* cd     = (const float*)d_in[1];
  const float* s      = (const float*)d_in[2];
  // d_in[3]=cs, d_in[4]=gx, d_in[5]=cgx unused by the reference
  const float* gy     = (const float*)d_in[6];
  const float* cgy    = (const float*)d_in[7];
  const float* spr    = (const float*)d_in[8];
  const float* w_prop = (const float*)d_in[9];
  const float* spw    = (const float*)d_in[10];
  const float* chw    = (const float*)d_in[11];
  const float* bias   = (const float*)d_in[12];
  float* out = (float*)d_out;

  float* params = (float*)d_ws;                       // 4096 floats reserved
  unsigned* I   = (unsigned*)d_ws + 4096;             // packed bf16 intermediate (33.5 MB)

  // K1 (+1 setup block folded in, runs concurrently with streaming blocks)
  k1_gyf<<<NB1 + 1, 256, 0, stream>>>(d, cd, s, gy, cgy, w_prop, spw, chw, params, I);

  k2_fused<<<NB2, 512, 0, stream>>>(I, spr, params, bias, out);
}